// Round 9
// baseline (175.093 us; speedup 1.0000x reference)
//
#include <hip/hip_runtime.h>
#include <hip/hip_bf16.h>
#include <cstdint>

// Problem constants (B=16, N=4096, D_IN=D_OUT=64)
#define NB   16
#define NN   4096
#define ND   64
#define NJ   1024   // NB*ND columns of the big GEMM

typedef __attribute__((ext_vector_type(8))) short  short8;  // 8 bf16 = 4 VGPRs
typedef __attribute__((ext_vector_type(4))) float  f32x4;

__device__ __forceinline__ unsigned short f2bf(float f) {
  union { float f; unsigned int u; } v; v.f = f;
  unsigned int u = v.u;
  unsigned int r = u + 0x7FFFu + ((u >> 16) & 1u);  // round-to-nearest-even
  return (unsigned short)(r >> 16);
}
__device__ __forceinline__ float bf2f(unsigned short h) {
  union { unsigned int u; float f; } v; v.u = ((unsigned int)h) << 16; return v.f;
}
__device__ __forceinline__ uint4 pack8(const float4 a, const float4 b) {
  uint4 o;
  o.x = (unsigned)f2bf(a.x) | ((unsigned)f2bf(a.y) << 16);
  o.y = (unsigned)f2bf(a.z) | ((unsigned)f2bf(a.w) << 16);
  o.z = (unsigned)f2bf(b.x) | ((unsigned)f2bf(b.y) << 16);
  o.w = (unsigned)f2bf(b.z) | ((unsigned)f2bf(b.w) << 16);
  return o;
}

// ---------------- K1: prep = {Yt = (Z W)^T} ONLY (A-convert fused into k_gemm) -----
// Round-9: the 96 MB A-convert round-trip (15us of prep) is eliminated; prep is now
// the round-5-verified zw kernel alone (LDS-staged coalesced Z, SMEM W).
__global__ void k_prep(const float* __restrict__ Z, const float* __restrict__ W,
                       unsigned short* __restrict__ Yt) {
  __shared__ float zs[64 * 65];                      // 16.25 KiB
  int bx = blockIdx.x;                               // [0,1024)
  int tid = threadIdx.x;
  int b  = bx >> 6;                  // [0,16)
  int m0 = (bx & 63) << 6;           // [0,4096) step 64
  const float* zb = Z + ((size_t)b * NN + m0) * ND;
#pragma unroll
  for (int r = 0; r < 4; ++r) {
    int row = r * 16 + (tid >> 4);
    int col = (tid & 15) * 4;
    float4 v = *(const float4*)(zb + (size_t)row * ND + col);
    float* d = &zs[row * 65 + col];
    d[0] = v.x; d[1] = v.y; d[2] = v.z; d[3] = v.w;   // 2 lanes/bank, free
  }
  __syncthreads();
  int lane = tid & 63;                               // = m-row within tile
  int e0 = __builtin_amdgcn_readfirstlane((tid >> 6) << 4);  // wave-uniform -> s_load W
  int m  = m0 + lane;
  float acc[16];
#pragma unroll
  for (int i = 0; i < 16; ++i) acc[i] = 0.f;
#pragma unroll
  for (int d = 0; d < 64; ++d) {
    float zd = zs[lane * 65 + d];                    // bank (lane+d)&31: free
#pragma unroll
    for (int i = 0; i < 16; ++i) acc[i] += zd * W[d * 64 + e0 + i];  // uniform -> SMEM
  }
#pragma unroll
  for (int i = 0; i < 16; ++i)
    Yt[(size_t)(b * 64 + e0 + i) * NN + m] = f2bf(acc[i]);
}

// ---------------- K2: 256x256-tile 8-phase GEMM, fused A fp32->bf16 staging ---------
// Grid 256 = 16m x 4j x 4kc, 1 block/CU, 512 thr = 8 waves (2M x 4N), per-wave 128x64.
// Round-9 delta: A staged from the ORIGINAL fp32 A via reg-staging (T14):
//   ph1: issue 8 global_load_dwordx4 (fp32) for A(t+1) into regs
//   ph4: vmcnt(4) [issue order B(t+1)4 < A(t+1)8 < B(t+2)4 = 16 in flight, drain 12
//        = B(t+1)+A(t+1)], f2bf-pack (bit-identical to old prep), 4x ds_write_b128
//        into the SAME chunk-XOR LDS image, lgkmcnt(0) before the barrier.
// B staging unchanged (global_load_lds from Yt). ds_read/MFMA machinery unchanged.
__device__ __forceinline__ void gl2lds16(const unsigned short* g, unsigned short* l) {
  __builtin_amdgcn_global_load_lds(
      (const __attribute__((address_space(1))) unsigned int*)g,
      (__attribute__((address_space(3))) unsigned int*)l, 16, 0, 0);
}

#define STAGE2(GP, LP, H) \
  gl2lds16((GP) + sOff[H][0], (LP) + dBase[H][0]); \
  gl2lds16((GP) + sOff[H][1], (LP) + dBase[H][1]);

#define READ_A(I0) \
  afr[0][0] = *(const short8*)&lt[aBase + (I0) * 1024 + c0]; \
  afr[0][1] = *(const short8*)&lt[aBase + (I0) * 1024 + c1]; \
  afr[1][0] = *(const short8*)&lt[aBase + ((I0) + 1) * 1024 + c0]; \
  afr[1][1] = *(const short8*)&lt[aBase + ((I0) + 1) * 1024 + c1];

#define MFMA_Q(I0) \
  _Pragma("unroll") \
  for (int jj = 0; jj < 4; ++jj) { \
    acc[(I0)][jj]     = __builtin_amdgcn_mfma_f32_16x16x32_bf16(afr[0][0], bfr[jj][0], acc[(I0)][jj], 0, 0, 0); \
    acc[(I0)][jj]     = __builtin_amdgcn_mfma_f32_16x16x32_bf16(afr[0][1], bfr[jj][1], acc[(I0)][jj], 0, 0, 0); \
    acc[(I0) + 1][jj] = __builtin_amdgcn_mfma_f32_16x16x32_bf16(afr[1][0], bfr[jj][0], acc[(I0) + 1][jj], 0, 0, 0); \
    acc[(I0) + 1][jj] = __builtin_amdgcn_mfma_f32_16x16x32_bf16(afr[1][1], bfr[jj][1], acc[(I0) + 1][jj], 0, 0, 0); \
  }

#define PHASE_MFMA(I0) \
  __builtin_amdgcn_s_barrier(); \
  asm volatile("" ::: "memory"); /* compiler fence; HW waits are data-dep lgkmcnt(N) */ \
  __builtin_amdgcn_s_setprio(1); \
  MFMA_Q(I0) \
  __builtin_amdgcn_s_setprio(0); \
  __builtin_amdgcn_s_barrier();

__launch_bounds__(512, 2)  // 8 waves, 1 block/CU (128 KiB LDS), VGPR cap 256
__global__ void k_gemm(const float* __restrict__ A,
                       const unsigned short* __restrict__ Yt,
                       unsigned short* __restrict__ Pb) {
  __shared__ unsigned short lds[65536];  // 128 KiB
  const int tid = threadIdx.x;
  const int w = tid >> 6, lane = tid & 63;
  const int quad = lane >> 4, l15 = lane & 15;
  const int wr = w >> 2, wc = w & 3;

  const int m_blk = blockIdx.x & 15;         // XCD = bx%8 = m_blk&7: 4 j_blks share
  const int j_blk = (blockIdx.x >> 4) & 3;   // one A strip per XCD L2
  const int kc    = blockIdx.x >> 6;
  const int mrow0 = m_blk << 8, jcol0 = j_blk << 8, kbase = kc << 10;

  const float* Agf = A + (size_t)mrow0 * 4096 + kbase;            // fp32 source
  const unsigned short* Bg = Yt + (size_t)jcol0 * 4096 + kbase;

  // B staging offsets (chunk-XOR): slot s -> row = s>>3, kg = (s&7)^(row&7).
  int sOff[2][2], dBase[2][2];
#pragma unroll
  for (int h = 0; h < 2; ++h)
#pragma unroll
    for (int r = 0; r < 2; ++r) {
      int s = h * 1024 + r * 512 + w * 64 + lane;
      int row = s >> 3;
      int kg = (s & 7) ^ (row & 7);
      sOff[h][r]  = row * 4096 + kg * 8;
      dBase[h][r] = (h * 1024 + r * 512 + w * 64) * 8;  // wave-uniform (shorts)
    }
  // A reg-staging offsets: chunk-group c (= h*2+r), per-lane slot s = c*512+w*64+lane.
  // Global fp32 elem offset = row*4096 + kg*8 (+4 for 2nd float4); LDS dst = s*8
  // shorts (identical image to gl2lds: uniform base + lane*16B).
  int srcAe[4], dA[4];
#pragma unroll
  for (int c = 0; c < 4; ++c) {
    int s = c * 512 + w * 64 + lane;
    int row = s >> 3;
    int kg = (s & 7) ^ (row & 7);
    srcAe[c] = row * 4096 + kg * 8;
    dA[c] = s * 8;
  }

  // ds_read chunk offsets (shorts): row&7 == l15&7 for all fragment rows.
  const int c0 = (quad ^ (l15 & 7)) * 8;
  const int c1 = ((4 + quad) ^ (l15 & 7)) * 8;
  const int aBase = (wr * 128 + l15) * 64;            // + i*1024 + c{0,1}
  const int bBase = 32768 + (wc * 64 + l15) * 64;     // + j*1024 + c{0,1} (rel. lds+p*16384)

  f32x4 acc[8][4];
#pragma unroll
  for (int i = 0; i < 8; ++i)
#pragma unroll
    for (int j = 0; j < 4; ++j) acc[i][j] = (f32x4){0.f, 0.f, 0.f, 0.f};

  float4 av[4][2];  // in-flight A(t+1) fp32 (32 VGPRs)

  // Prologue: A(0) reg-loads (8), B(0) gl2lds (4), B(1) gl2lds (4) = 16 in flight.
  // vmcnt(4) drains oldest 12 = A(0)+B(0); pack+write A(0) -> buf0; B(1) flies.
#pragma unroll
  for (int cidx = 0; cidx < 4; ++cidx) {
    const float* gp = Agf + srcAe[cidx];
    av[cidx][0] = ((const float4*)gp)[0];
    av[cidx][1] = ((const float4*)gp)[1];
  }
  STAGE2(Bg, lds + 32768, 0) STAGE2(Bg, lds + 32768, 1)
  STAGE2(Bg + 64, lds + 49152, 0) STAGE2(Bg + 64, lds + 49152, 1)
  asm volatile("s_waitcnt vmcnt(4)" ::: "memory");
#pragma unroll
  for (int cidx = 0; cidx < 4; ++cidx)
    *(uint4*)&lds[dA[cidx]] = pack8(av[cidx][0], av[cidx][1]);
  asm volatile("s_waitcnt lgkmcnt(0)" ::: "memory");
  __builtin_amdgcn_s_barrier();

  for (int t = 0; t < 16; ++t) {
    const int p = t & 1;
    const unsigned short* lt = lds + p * 16384;
    short8 bfr[4][2], afr[2][2];

    // ---- phase 1: all B-frags + A-quad0; ISSUE A(t+1) fp32 reg-loads (8) ----
#pragma unroll
    for (int j = 0; j < 4; ++j) {
      bfr[j][0] = *(const short8*)&lt[bBase + j * 1024 + c0];
      bfr[j][1] = *(const short8*)&lt[bBase + j * 1024 + c1];
    }
    READ_A(0)
    if (t < 15) {
      const float* gt = Agf + (t + 1) * 64;
#pragma unroll
      for (int cidx = 0; cidx < 4; ++cidx) {
        const float* gp = gt + srcAe[cidx];
        av[cidx][0] = ((const float4*)gp)[0];
        av[cidx][1] = ((const float4*)gp)[1];
      }
    }
    asm volatile("s_waitcnt lgkmcnt(8)" ::: "memory");  // 12 ds_reads this phase
    PHASE_MFMA(0)

    // ---- phase 2: A-quad1; stage B(t+2) half 0 (tile-t B region read in ph1) ----
    READ_A(2)
    if (t < 14) {
      const unsigned short* g = Bg + (t + 2) * 64;
      unsigned short* lb = lds + 32768 + p * 16384;
      STAGE2(g, lb, 0)
    }
    PHASE_MFMA(2)

    // ---- phase 3: A-quad2; stage B(t+2) half 1 ----
    READ_A(4)
    if (t < 14) {
      const unsigned short* g = Bg + (t + 2) * 64;
      unsigned short* lb = lds + 32768 + p * 16384;
      STAGE2(g, lb, 1)
    }
    PHASE_MFMA(4)

    // ---- phase 4: A-quad3; counted vmcnt; pack+write A(t+1) into buf p^1 ----
    READ_A(6)
    if (t < 15) {
      if (t < 14) { asm volatile("s_waitcnt vmcnt(4)" ::: "memory"); }  // B(t+2) flies
      else        { asm volatile("s_waitcnt vmcnt(0)" ::: "memory"); }  // t==14: drain
      unsigned short* lb = lds + (p ^ 1) * 16384;
#pragma unroll
      for (int cidx = 0; cidx < 4; ++cidx)
        *(uint4*)&lb[dA[cidx]] = pack8(av[cidx][0], av[cidx][1]);
      asm volatile("s_waitcnt lgkmcnt(0)" ::: "memory");  // writes visible pre-barrier
    }
    PHASE_MFMA(6)
  }

  // Epilogue: C/D layout col=l15, row=quad*4+reg (m89/m91-verified mapping).
  unsigned short* P = Pb + (size_t)kc * ((size_t)NN * NJ);
  const int r0base = mrow0 + wr * 128;
  const int cb = jcol0 + wc * 64;
#pragma unroll
  for (int i = 0; i < 8; ++i) {
    const int r0 = r0base + i * 16 + quad * 4;
#pragma unroll
    for (int j = 0; j < 4; ++j) {
      const int jc = cb + j * 16 + l15;
      unsigned short* pp = P + (size_t)r0 * NJ + jc;
#pragma unroll
      for (int rg = 0; rg < 4; ++rg)
        pp[(size_t)rg * NJ] = f2bf(acc[i][j][rg]);
    }
  }
}

// ---------------- K3: out[m-major] = sum_kc P[kc]; 8 floats/thread ------------------
__global__ void k_reduce(const unsigned short* __restrict__ P, float* __restrict__ out) {
  int t = blockIdx.x * 256 + threadIdx.x;      // 524,288 threads exactly
  size_t of = (size_t)t * 8;                   // out flat index (8 consecutive floats)
  int bidx = t >> 15;                          // of >> 18
  int rem  = (int)(of & 262143);               // within one batch: m*64 + e
  int m = rem >> 6, e = rem & 63;
  size_t pj = (size_t)m * NJ + bidx * 64 + e;  // P row-index: [m][j= bidx*64+e]
  float s[8];
#pragma unroll
  for (int u = 0; u < 8; ++u) s[u] = 0.f;
#pragma unroll
  for (int kc = 0; kc < 4; ++kc) {
    short8 v = *(const short8*)(P + (size_t)kc * (NN * NJ) + pj);  // 16B load
#pragma unroll
    for (int u = 0; u < 8; ++u) s[u] += bf2f((unsigned short)v[u]);
  }
  float4 o0 = {s[0], s[1], s[2], s[3]}, o1 = {s[4], s[5], s[6], s[7]};
  ((float4*)(out + of))[0] = o0;
  ((float4*)(out + of))[1] = o1;
}

extern "C" void kernel_launch(void* const* d_in, const int* in_sizes, int n_in,
                              void* d_out, int out_size, void* d_ws, size_t ws_size,
                              hipStream_t stream) {
  const float* Z = (const float*)d_in[0];   // [16][4096][64] fp32
  const float* A = (const float*)d_in[1];   // [4096][4096] fp32
  const float* W = (const float*)d_in[2];   // [64][64] fp32
  float* out = (float*)d_out;               // [16][4096][64] fp32

  unsigned short* Yt = (unsigned short*)d_ws;                                     // 8 MiB bf16 Y^T
  unsigned short* Pb = (unsigned short*)((char*)d_ws + (size_t)8 * 1024 * 1024);  // 32 MiB bf16 partials x4

  k_prep<<<1024, 256, 0, stream>>>(Z, W, Yt);
  k_gemm<<<256, 512, 0, stream>>>(A, Yt, Pb);
  k_reduce<<<2048, 256, 0, stream>>>(Pb, out);
}

// Round 10
// 157.926 us; speedup vs baseline: 1.1087x; 1.1087x over previous
//
#include <hip/hip_runtime.h>
#include <hip/hip_bf16.h>
#include <cstdint>

// Problem constants (B=16, N=4096, D_IN=D_OUT=64)
#define NB   16
#define NN   4096
#define ND   64
#define NJ   1024   // NB*ND columns of the big GEMM

typedef __attribute__((ext_vector_type(8))) short  short8;  // 8 bf16 = 4 VGPRs
typedef __attribute__((ext_vector_type(4))) float  f32x4;

__device__ __forceinline__ unsigned short f2bf(float f) {
  union { float f; unsigned int u; } v; v.f = f;
  unsigned int u = v.u;
  unsigned int r = u + 0x7FFFu + ((u >> 16) & 1u);  // round-to-nearest-even
  return (unsigned short)(r >> 16);
}
__device__ __forceinline__ float bf2f(unsigned short h) {
  union { unsigned int u; float f; } v; v.u = ((unsigned int)h) << 16; return v.f;
}

// ---------------- K1: merged prep = {Yt = (Z W)^T} + {A fp32->bf16 convert} --------
// Round-6-verified version (round-9's gemm-fused A-convert regressed; reverted).
// zw blocks FIRST (bx < 1024): latency-bound, hides under the BW-bound convert.
__global__ void k_prep(const float* __restrict__ A, const float* __restrict__ Z,
                       const float* __restrict__ W, unsigned short* __restrict__ Ab,
                       unsigned short* __restrict__ Yt) {
  __shared__ float zs[64 * 65];                      // 16.25 KiB (zw blocks only)
  int bx = blockIdx.x;
  int tid = threadIdx.x;
  if (bx < 1024) {
    int b  = bx >> 6;                  // [0,16)
    int m0 = (bx & 63) << 6;           // [0,4096) step 64
    const float* zb = Z + ((size_t)b * NN + m0) * ND;
#pragma unroll
    for (int r = 0; r < 4; ++r) {
      int row = r * 16 + (tid >> 4);
      int col = (tid & 15) * 4;
      float4 v = *(const float4*)(zb + (size_t)row * ND + col);
      float* d = &zs[row * 65 + col];
      d[0] = v.x; d[1] = v.y; d[2] = v.z; d[3] = v.w;   // 2 lanes/bank, free
    }
    __syncthreads();
    int lane = tid & 63;                               // = m-row within tile
    int e0 = __builtin_amdgcn_readfirstlane((tid >> 6) << 4);  // wave-uniform -> s_load W
    int m  = m0 + lane;
    float acc[16];
#pragma unroll
    for (int i = 0; i < 16; ++i) acc[i] = 0.f;
#pragma unroll
    for (int d = 0; d < 64; ++d) {
      float zd = zs[lane * 65 + d];                    // bank (lane+d)&31: free
#pragma unroll
      for (int i = 0; i < 16; ++i) acc[i] += zd * W[d * 64 + e0 + i];  // uniform -> SMEM
    }
#pragma unroll
    for (int i = 0; i < 16; ++i)
      Yt[(size_t)(b * 64 + e0 + i) * NN + m] = f2bf(acc[i]);
  } else {
    int idx = (bx - 1024) * 256 + tid;               // 2,097,152 threads exactly
    const float4* p = (const float4*)A + (size_t)idx * 2;
    float4 a = p[0], b = p[1];
    unsigned int w0 = (unsigned int)f2bf(a.x) | ((unsigned int)f2bf(a.y) << 16);
    unsigned int w1 = (unsigned int)f2bf(a.z) | ((unsigned int)f2bf(a.w) << 16);
    unsigned int w2 = (unsigned int)f2bf(b.x) | ((unsigned int)f2bf(b.y) << 16);
    unsigned int w3 = (unsigned int)f2bf(b.z) | ((unsigned int)f2bf(b.w) << 16);
    uint4 o; o.x = w0; o.y = w1; o.z = w2; o.w = w3;
    ((uint4*)Ab)[idx] = o;                           // 16B store
  }
}

// ---------------- K2: 256x256-tile 8-phase GEMM, DEPTH-2 A prefetch -----------------
// Grid 256 = 16m x 4j x 4kc, 1 block/CU, 512 thr = 8 waves (2M x 4N), per-wave 128x64.
// Round-10 delta: A triple-buffered (3x32KB) + B double (2x32KB) = 160 KB LDS.
// Both A(t+2) and B(t+2) staged during tile t (2 gl2lds/phase, even); steady
// vmcnt(8) at ph4 drains exactly A(t+1)+B(t+1) -- both issued a FULL TILE earlier
// (4-7 phases ~5000cy vs A's previous 3-phase window). Theory: the constant
// ~3900cy/tile stall (invariant across r6 spread & r8 occupancy) is A-latency tail
// at the per-tile vmcnt; depth-2 removes it (m201's 3-half-tile in-flight analog).
__device__ __forceinline__ void gl2lds16(const unsigned short* g, unsigned short* l) {
  __builtin_amdgcn_global_load_lds(
      (const __attribute__((address_space(1))) unsigned int*)g,
      (__attribute__((address_space(3))) unsigned int*)l, 16, 0, 0);
}

#define STAGE2(GP, LP, H) \
  gl2lds16((GP) + sOff[H][0], (LP) + dBase[H][0]); \
  gl2lds16((GP) + sOff[H][1], (LP) + dBase[H][1]);

#define READ_A(I0) \
  afr[0][0] = *(const short8*)&la[aBase + (I0) * 1024 + c0]; \
  afr[0][1] = *(const short8*)&la[aBase + (I0) * 1024 + c1]; \
  afr[1][0] = *(const short8*)&la[aBase + ((I0) + 1) * 1024 + c0]; \
  afr[1][1] = *(const short8*)&la[aBase + ((I0) + 1) * 1024 + c1];

#define MFMA_Q(I0) \
  _Pragma("unroll") \
  for (int jj = 0; jj < 4; ++jj) { \
    acc[(I0)][jj]     = __builtin_amdgcn_mfma_f32_16x16x32_bf16(afr[0][0], bfr[jj][0], acc[(I0)][jj], 0, 0, 0); \
    acc[(I0)][jj]     = __builtin_amdgcn_mfma_f32_16x16x32_bf16(afr[0][1], bfr[jj][1], acc[(I0)][jj], 0, 0, 0); \
    acc[(I0) + 1][jj] = __builtin_amdgcn_mfma_f32_16x16x32_bf16(afr[1][0], bfr[jj][0], acc[(I0) + 1][jj], 0, 0, 0); \
    acc[(I0) + 1][jj] = __builtin_amdgcn_mfma_f32_16x16x32_bf16(afr[1][1], bfr[jj][1], acc[(I0) + 1][jj], 0, 0, 0); \
  }

#define PHASE_MFMA(I0) \
  __builtin_amdgcn_s_barrier(); \
  asm volatile("" ::: "memory"); /* compiler fence; HW waits are data-dep lgkmcnt(N) */ \
  __builtin_amdgcn_s_setprio(1); \
  MFMA_Q(I0) \
  __builtin_amdgcn_s_setprio(0); \
  __builtin_amdgcn_s_barrier();

__launch_bounds__(512, 2)  // 8 waves, 1 block/CU (160 KiB LDS)
__global__ void k_gemm(const unsigned short* __restrict__ Ab,
                       const unsigned short* __restrict__ Yt,
                       unsigned short* __restrict__ Pb) {
  __shared__ unsigned short lds[81920];  // 160 KiB: A 3x16384 @0, B 2x16384 @49152
  const int tid = threadIdx.x;
  const int w = tid >> 6, lane = tid & 63;
  const int quad = lane >> 4, l15 = lane & 15;
  const int wr = w >> 2, wc = w & 3;

  const int m_blk = blockIdx.x & 15;         // XCD = bx%8 = m_blk&7: 4 j_blks share
  const int j_blk = (blockIdx.x >> 4) & 3;   // one A strip per XCD L2
  const int kc    = blockIdx.x >> 6;
  const int mrow0 = m_blk << 8, jcol0 = j_blk << 8, kbase = kc << 10;

  const unsigned short* Ag = Ab + (size_t)mrow0 * 4096 + kbase;
  const unsigned short* Bg = Yt + (size_t)jcol0 * 4096 + kbase;

  // Staging offsets: half h, round r -> uniform LDS slot base h*1024+r*512+w*64,
  // per-lane slot s = base+lane, global source (row=s>>3, kg=(s&7)^(row&7)).
  int sOff[2][2], dBase[2][2];
#pragma unroll
  for (int h = 0; h < 2; ++h)
#pragma unroll
    for (int r = 0; r < 2; ++r) {
      int s = h * 1024 + r * 512 + w * 64 + lane;
      int row = s >> 3;
      int kg = (s & 7) ^ (row & 7);
      sOff[h][r]  = row * 4096 + kg * 8;
      dBase[h][r] = (h * 1024 + r * 512 + w * 64) * 8;  // wave-uniform (shorts)
    }

  // ds_read chunk offsets (shorts): row&7 == l15&7 for all fragment rows.
  const int c0 = (quad ^ (l15 & 7)) * 8;
  const int c1 = ((4 + quad) ^ (l15 & 7)) * 8;
  const int aBase = (wr * 128 + l15) * 64;     // + i*1024 + c{0,1}, rel. A-buf
  const int bBase = (wc * 64 + l15) * 64;      // + j*1024 + c{0,1}, rel. B-buf

  f32x4 acc[8][4];
#pragma unroll
  for (int i = 0; i < 8; ++i)
#pragma unroll
    for (int j = 0; j < 4; ++j) acc[i][j] = (f32x4){0.f, 0.f, 0.f, 0.f};

  // Prologue: A(0)->A0, B(0)->B0, A(1)->A1, B(1)->B1 (16 loads).
  // vmcnt(8): oldest 8 (= tile0's A+B) landed; tile1's 8 still in flight.
  STAGE2(Ag, lds, 0) STAGE2(Ag, lds, 1)
  STAGE2(Bg, lds + 49152, 0) STAGE2(Bg, lds + 49152, 1)
  STAGE2(Ag + 64, lds + 16384, 0) STAGE2(Ag + 64, lds + 16384, 1)
  STAGE2(Bg + 64, lds + 65536, 0) STAGE2(Bg + 64, lds + 65536, 1)
  asm volatile("s_waitcnt vmcnt(8)" ::: "memory");
  __builtin_amdgcn_s_barrier();

  int ac = 0;                                  // A read-buf = t % 3
  for (int t = 0; t < 16; ++t) {
    const int p = t & 1;
    const unsigned short* la = lds + ac * 16384;
    const unsigned short* lb = lds + 49152 + p * 16384;
    int aw = ac + 2; if (aw >= 3) aw -= 3;     // A write-buf = (t+2) % 3
    short8 bfr[4][2], afr[2][2];

    // ---- phase 1: all B-frags + A-quad0; stage A(t+2) half 0 ----
    // (A(t-1) buf aw: all its ds_reads physically completed before t-1 ph4's
    //  trailing barrier, so writes issued now land safely after.)
#pragma unroll
    for (int j = 0; j < 4; ++j) {
      bfr[j][0] = *(const short8*)&lb[bBase + j * 1024 + c0];
      bfr[j][1] = *(const short8*)&lb[bBase + j * 1024 + c1];
    }
    READ_A(0)
    if (t < 14) {
      const unsigned short* g = Ag + (t + 2) * 64;
      unsigned short* lw = lds + aw * 16384;
      STAGE2(g, lw, 0)
    }
    asm volatile("s_waitcnt lgkmcnt(8)" ::: "memory");  // 12 ds_reads this phase
    PHASE_MFMA(0)

    // ---- phase 2: A-quad1; stage A(t+2) half 1 ----
    READ_A(2)
    if (t < 14) {
      const unsigned short* g = Ag + (t + 2) * 64;
      unsigned short* lw = lds + aw * 16384;
      STAGE2(g, lw, 1)
    }
    PHASE_MFMA(2)

    // ---- phase 3: A-quad2; stage B(t+2) half 0 (buf p: B(t) read only in ph1,
    //      reads complete before ph1's trailing barrier -> safe, as r1/r6) ----
    READ_A(4)
    if (t < 14) {
      const unsigned short* g = Bg + (t + 2) * 64;
      unsigned short* lw = lds + 49152 + p * 16384;
      STAGE2(g, lw, 0)
    }
    PHASE_MFMA(4)

    // ---- phase 4: A-quad3; stage B(t+2) half 1; counted vmcnt(8) once/tile:
    //      16 in flight, drain oldest 8 = A(t+1)+B(t+1), issued a full tile ago ----
    READ_A(6)
    if (t < 14) {
      const unsigned short* g = Bg + (t + 2) * 64;
      unsigned short* lw = lds + 49152 + p * 16384;
      STAGE2(g, lw, 1)
    }
    if (t < 14)      { asm volatile("s_waitcnt vmcnt(8)" ::: "memory"); }
    else if (t == 14){ asm volatile("s_waitcnt vmcnt(0)" ::: "memory"); }
    PHASE_MFMA(6)

    ++ac; if (ac >= 3) ac = 0;
  }

  // Epilogue: C/D layout col=l15, row=quad*4+reg (m89/m91-verified mapping).
  unsigned short* P = Pb + (size_t)kc * ((size_t)NN * NJ);
  const int r0base = mrow0 + wr * 128;
  const int cb = jcol0 + wc * 64;
#pragma unroll
  for (int i = 0; i < 8; ++i) {
    const int r0 = r0base + i * 16 + quad * 4;
#pragma unroll
    for (int j = 0; j < 4; ++j) {
      const int jc = cb + j * 16 + l15;
      unsigned short* pp = P + (size_t)r0 * NJ + jc;
#pragma unroll
      for (int rg = 0; rg < 4; ++rg)
        pp[(size_t)rg * NJ] = f2bf(acc[i][j][rg]);
    }
  }
}

// ---------------- K3: out[m-major] = sum_kc P[kc]; 8 floats/thread ------------------
__global__ void k_reduce(const unsigned short* __restrict__ P, float* __restrict__ out) {
  int t = blockIdx.x * 256 + threadIdx.x;      // 524,288 threads exactly
  size_t of = (size_t)t * 8;                   // out flat index (8 consecutive floats)
  int bidx = t >> 15;                          // of >> 18
  int rem  = (int)(of & 262143);               // within one batch: m*64 + e
  int m = rem >> 6, e = rem & 63;
  size_t pj = (size_t)m * NJ + bidx * 64 + e;  // P row-index: [m][j= bidx*64+e]
  float s[8];
#pragma unroll
  for (int u = 0; u < 8; ++u) s[u] = 0.f;
#pragma unroll
  for (int kc = 0; kc < 4; ++kc) {
    short8 v = *(const short8*)(P + (size_t)kc * (NN * NJ) + pj);  // 16B load
#pragma unroll
    for (int u = 0; u < 8; ++u) s[u] += bf2f((unsigned short)v[u]);
  }
  float4 o0 = {s[0], s[1], s[2], s[3]}, o1 = {s[4], s[5], s[6], s[7]};
  ((float4*)(out + of))[0] = o0;
  ((float4*)(out + of))[1] = o1;
}

extern "C" void kernel_launch(void* const* d_in, const int* in_sizes, int n_in,
                              void* d_out, int out_size, void* d_ws, size_t ws_size,
                              hipStream_t stream) {
  const float* Z = (const float*)d_in[0];   // [16][4096][64] fp32
  const float* A = (const float*)d_in[1];   // [4096][4096] fp32
  const float* W = (const float*)d_in[2];   // [64][64] fp32
  float* out = (float*)d_out;               // [16][4096][64] fp32

  unsigned short* Ab = (unsigned short*)d_ws;                                     // 32 MiB bf16 A
  unsigned short* Yt = (unsigned short*)((char*)d_ws + (size_t)32 * 1024 * 1024); // 8 MiB bf16 Y^T
  unsigned short* Pb = (unsigned short*)((char*)d_ws + (size_t)40 * 1024 * 1024); // 32 MiB bf16 partials x4

  k_prep<<<9216, 256, 0, stream>>>(A, Z, W, Ab, Yt);
  k_gemm<<<256, 512, 0, stream>>>(Ab, Yt, Pb);
  k_reduce<<<2048, 256, 0, stream>>>(Pb, out);
}